// Round 1
// baseline (871.754 us; speedup 1.0000x reference)
//
#include <hip/hip_runtime.h>

// BsplineEncoding: N=1M points, D=3, K=64, cubic.
// Output row per point: [x0, feat0[64], x1, feat1[64], x2, feat2[64]] = 195 fp32.
// Write-bound: 780 MB output per call (harness poisons d_out each call).
//
// Structure: 1 block (256 thr) per 64 points.
//   Phase 1: coalesced float4 zero-fill of the block's 12480-float span.
//   __syncthreads() orders global stores block-wide (compiler drains vmcnt).
//   Phase 2: 192 threads scatter the 5 nonzero values per (point,dim);
//            overwrites hit L2-resident lines -> no extra HBM traffic.

constexpr int   DIMS        = 3;
constexpr int   K           = 64;
constexpr int   ROW         = DIMS * (1 + K);          // 195 floats
constexpr float SCALE       = 30.5f;                   // (K-3)/(1-(-1))
constexpr float CLAMP_MAX   = 61.0f - 1e-6f;           // K-DEG-EPS
constexpr int   PTS_PER_BLK = 64;
constexpr int   FLT_PER_BLK = PTS_PER_BLK * ROW;       // 12480
constexpr int   V4_PER_BLK  = FLT_PER_BLK / 4;         // 3120

__global__ __launch_bounds__(256)
void bspline_kernel(const float* __restrict__ x, float* __restrict__ out,
                    int n_points) {
    const int t = threadIdx.x;
    const long long block_base = (long long)blockIdx.x * FLT_PER_BLK;
    const long long total_flt  = (long long)n_points * ROW;

    // ---- Phase 1: zero-fill this block's output span (vectorized) ----
    float4* out4 = reinterpret_cast<float4*>(out + block_base);
    // number of full float4s this block may write (guards the last block)
    long long rem = total_flt - block_base;            // floats remaining
    int lim = (rem >= FLT_PER_BLK) ? V4_PER_BLK : (int)(rem > 0 ? rem / 4 : 0);
    for (int f = t; f < lim; f += 256) {
        out4[f] = make_float4(0.f, 0.f, 0.f, 0.f);
    }

    __syncthreads();   // global-store ordering within block

    // ---- Phase 2: scatter the nonzero entries ----
    if (t < PTS_PER_BLK * DIMS) {
        const int nl = t / 3;
        const int d  = t - nl * 3;
        const int n  = blockIdx.x * PTS_PER_BLK + nl;
        if (n < n_points) {
            const float xv = x[n * 3 + d];
            float xs = (xv + 1.0f) * SCALE;
            xs = fminf(fmaxf(xs, 0.0f), CLAMP_MAX);
            const int   idx = (int)xs;                 // xs >= 0, trunc == floor
            const float u   = xs - (float)idx;
            const float u2  = u * u;
            const float u3  = u2 * u;
            const float om  = 1.0f - u;
            const float c0  = om * om * om * (1.0f / 6.0f);
            const float c1  = (3.0f * u3 - 6.0f * u2 + 4.0f) * (1.0f / 6.0f);
            const float c2  = (-3.0f * u3 + 3.0f * u2 + 3.0f * u + 1.0f) * (1.0f / 6.0f);
            const float c3  = u3 * (1.0f / 6.0f);

            float* row = out + (long long)n * ROW + d * (1 + K);
            row[0] = xv;
            float* fptr = row + 1 + idx;
            fptr[0] = c0;
            fptr[1] = c1;
            fptr[2] = c2;
            fptr[3] = c3;
        }
    }
}

extern "C" void kernel_launch(void* const* d_in, const int* in_sizes, int n_in,
                              void* d_out, int out_size, void* d_ws, size_t ws_size,
                              hipStream_t stream) {
    const float* x  = (const float*)d_in[0];
    float* out      = (float*)d_out;
    const int n_pts = in_sizes[0] / DIMS;              // 1,000,000
    const int nblk  = (n_pts + PTS_PER_BLK - 1) / PTS_PER_BLK;  // 15625
    bspline_kernel<<<dim3(nblk), dim3(256), 0, stream>>>(x, out, n_pts);
}

// Round 2
// 768.612 us; speedup vs baseline: 1.1342x; 1.1342x over previous
//
#include <hip/hip_runtime.h>

// BsplineEncoding: N=1M, D=3, K=64, cubic. Row = 3*(1+64) = 195 fp32/point.
// R1 post-mortem: two-phase global (bulk zero + scattered dword overwrite)
// caused HBM read-modify-write on ~every line (phase-1 lines evicted from the
// 4 MiB/XCD L2 before phase-2 hit them) -> ~2.1 GB HBM traffic instead of
// 0.79 GB. Fix: assemble rows in LDS, write each global line EXACTLY once.
//
// Block = 256 threads, 64 points, 48.75 KB LDS (3 blocks/CU -> 12 waves/CU,
// enough for a store-bound stream; harness fill hits 78% peak at 10% occ).

constexpr int   DIMS        = 3;
constexpr int   K           = 64;
constexpr int   ROW         = DIMS * (1 + K);          // 195 floats
constexpr float SCALE       = 30.5f;                   // (K-3)/2
constexpr float CLAMP_MAX   = 61.0f - 1e-6f;           // K-DEG-EPS
constexpr int   PTS_PER_BLK = 64;
constexpr int   FLT_PER_BLK = PTS_PER_BLK * ROW;       // 12480 floats = 48.75 KB
constexpr int   V4_PER_BLK  = FLT_PER_BLK / 4;         // 3120

__global__ __launch_bounds__(256)
void bspline_kernel(const float* __restrict__ x, float* __restrict__ out,
                    int n_points) {
    __shared__ __align__(16) float lds[FLT_PER_BLK];
    const int t = threadIdx.x;

    // ---- Phase 1: zero LDS (vectorized, conflict-free stride-1) ----
    float4* lds4 = reinterpret_cast<float4*>(lds);
    for (int f = t; f < V4_PER_BLK; f += 256) {
        lds4[f] = make_float4(0.f, 0.f, 0.f, 0.f);
    }
    __syncthreads();

    // ---- Phase 2: 192 threads compute one (point,dim) each, scatter to LDS ----
    if (t < PTS_PER_BLK * DIMS) {
        const int nl = t / 3;                  // local point 0..63
        const int d  = t - nl * 3;             // dim 0..2
        const int n  = blockIdx.x * PTS_PER_BLK + nl;
        if (n < n_points) {
            // x index = blockIdx*192 + t  -> fully coalesced load
            const float xv = x[(long long)n * 3 + d];
            float xs = (xv + 1.0f) * SCALE;
            xs = fminf(fmaxf(xs, 0.0f), CLAMP_MAX);
            const int   idx = (int)xs;         // xs >= 0 -> trunc == floor
            const float u   = xs - (float)idx;
            const float u2  = u * u;
            const float u3  = u2 * u;
            const float om  = 1.0f - u;
            const float c0  = om * om * om * (1.0f / 6.0f);
            const float c1  = (3.0f * u3 - 6.0f * u2 + 4.0f) * (1.0f / 6.0f);
            const float c2  = (-3.0f * u3 + 3.0f * u2 + 3.0f * u + 1.0f) * (1.0f / 6.0f);
            const float c3  = u3 * (1.0f / 6.0f);

            float* row = lds + nl * ROW + d * (1 + K);
            row[0] = xv;
            float* fptr = row + 1 + idx;
            fptr[0] = c0;
            fptr[1] = c1;
            fptr[2] = c2;
            fptr[3] = c3;
        }
    }
    __syncthreads();

    // ---- Phase 3: coalesced single-write stream LDS -> global ----
    const long long block_base = (long long)blockIdx.x * FLT_PER_BLK;
    const long long total_flt  = (long long)n_points * ROW;
    long long rem = total_flt - block_base;
    const int lim = (rem >= FLT_PER_BLK) ? V4_PER_BLK
                                         : (int)(rem > 0 ? rem / 4 : 0);
    float4* out4 = reinterpret_cast<float4*>(out + block_base);
    for (int f = t; f < lim; f += 256) {
        out4[f] = lds4[f];
    }
}

extern "C" void kernel_launch(void* const* d_in, const int* in_sizes, int n_in,
                              void* d_out, int out_size, void* d_ws, size_t ws_size,
                              hipStream_t stream) {
    const float* x  = (const float*)d_in[0];
    float* out      = (float*)d_out;
    const int n_pts = in_sizes[0] / DIMS;                        // 1,000,000
    const int nblk  = (n_pts + PTS_PER_BLK - 1) / PTS_PER_BLK;   // 15625
    bspline_kernel<<<dim3(nblk), dim3(256), 0, stream>>>(x, out, n_pts);
}